// Round 8
// baseline (576.336 us; speedup 1.0000x reference)
//
#include <hip/hip_runtime.h>
#include <cstdint>

#define K_CODES 8192
#define D_DIM   256
#define N_TOT   16384
#define HW      1024
#define KSPLIT  64
#define BN      128
#define BK      128                      // codes per block == slice size

typedef _Float16 f16;
typedef _Float16 f16x8 __attribute__((ext_vector_type(8)));
typedef float    f32x4 __attribute__((ext_vector_type(4)));

// ---------------------------------------------------------------------------
// prep_z: ONE strided pass over z_e producing both the numpy-pairwise zn2
// (verified bit-exact R6/R7) and the f16 2-term split z3 (hi | lo*2048).
// ---------------------------------------------------------------------------
__global__ __launch_bounds__(256) void prep_z_kernel(const float* __restrict__ z_e,
                                                     f16* __restrict__ z3,
                                                     float* __restrict__ zn2) {
    #pragma clang fp contract(off)
    const int n = blockIdx.x * 256 + threadIdx.x;
    const int b = n >> 10, hw = n & (HW - 1);
    const float* p = z_e + (size_t)b * (D_DIM * HW) + hw;
    f16* o = z3 + (size_t)n * 512;
    float blk[2];
    #pragma unroll
    for (int b2 = 0; b2 < 2; ++b2) {
        float r[8];
        #pragma unroll
        for (int j = 0; j < 8; ++j) {
            const int d = b2 * 128 + j;
            const float v = p[(size_t)d * HW];
            const f16 h = (f16)v;
            o[d] = h; o[256 + d] = (f16)((v - (float)h) * 2048.0f);
            r[j] = v * v;
        }
        for (int i = 8; i < 128; i += 8) {
            #pragma unroll
            for (int j = 0; j < 8; ++j) {
                const int d = b2 * 128 + i + j;
                const float v = p[(size_t)d * HW];
                const f16 h = (f16)v;
                o[d] = h; o[256 + d] = (f16)((v - (float)h) * 2048.0f);
                r[j] += v * v;
            }
        }
        blk[b2] = ((r[0] + r[1]) + (r[2] + r[3])) + ((r[4] + r[5]) + (r[6] + r[7]));
    }
    zn2[n] = blk[0] + blk[1];
}

// prep_c: same fusion for the codebook (contiguous rows, c pre-scaled 4096)
__global__ __launch_bounds__(256) void prep_c_kernel(const float* __restrict__ emb,
                                                     f16* __restrict__ c3,
                                                     float* __restrict__ cn2) {
    #pragma clang fp contract(off)
    const int k = blockIdx.x * 256 + threadIdx.x;
    const float* p = emb + (size_t)k * D_DIM;
    f16* o = c3 + (size_t)k * 512;
    float blk[2];
    #pragma unroll
    for (int b2 = 0; b2 < 2; ++b2) {
        float r[8];
        #pragma unroll
        for (int j = 0; j < 8; ++j) {
            const int d = b2 * 128 + j;
            const float v = p[d];
            const float vs = v * 4096.0f;
            const f16 h = (f16)vs;
            o[d] = h; o[256 + d] = (f16)((vs - (float)h) * 2048.0f);
            r[j] = v * v;
        }
        for (int i = 8; i < 128; i += 8) {
            #pragma unroll
            for (int j = 0; j < 8; ++j) {
                const int d = b2 * 128 + i + j;
                const float v = p[d];
                const float vs = v * 4096.0f;
                const f16 h = (f16)vs;
                o[d] = h; o[256 + d] = (f16)((vs - (float)h) * 2048.0f);
                r[j] += v * v;
            }
        }
        blk[b2] = ((r[0] + r[1]) + (r[2] + r[3])) + ((r[4] + r[5]) + (r[6] + r[7]));
    }
    cn2[k] = blk[0] + blk[1];
}

__global__ void init_packed_kernel(unsigned long long* __restrict__ packed) {
    packed[blockIdx.x * 256 + threadIdx.x] = ~0ULL;
}

__device__ __forceinline__ void gll16(const void* g, void* l) {
    __builtin_amdgcn_global_load_lds(
        (const __attribute__((address_space(1))) unsigned int*)g,
        (__attribute__((address_space(3))) unsigned int*)l, 16, 0, 0);
}

// ---------------------------------------------------------------------------
// Main MFMA kernel. grid (KSPLIT=64, N_TOT/BN=128): block = one (nb, ks) pair,
// z and c each staged EXACTLY ONCE (no re-reads -> fetch ~= unique data).
// XCD = flat_bid%8 = ks%8: 8 c-slices/XCD = 1 MB, L2-resident; same-nb blocks
// are 64 consecutive bids -> co-resident, z fetch shared via L2/L3.
// 4 waves (wr,wc), 64n x 64k per wave, 4x4 frags of mfma_f32_16x16x32_f16,
// 3 split-products (hh -> acc1, hl+lh -> acc2), dbuf LDS, 16B-block XOR
// swizzle with pre-swizzled global source (R7-verified, conflicts = 0).
// Result merged globally via u64 atomicMin: (bits(v)<<32)|idx, v~=256>0, so
// u64-min == (min v, then min idx) == numpy argmin tie-break.
// ---------------------------------------------------------------------------
__global__ __launch_bounds__(256, 2) void vq_mfma_kernel(
        const f16* __restrict__ z3, const f16* __restrict__ c3,
        const float* __restrict__ zn2, const float* __restrict__ cn2,
        unsigned long long* __restrict__ packed) {
    __shared__ __align__(16) char lds[2 * 32768];

    const int tid = threadIdx.x;
    const int w = tid >> 6, l = tid & 63;
    const int wr = w >> 1, wc = w & 1;
    const int g = l >> 4, li = l & 15;
    const int ks = blockIdx.x;
    const int nb = blockIdx.y * BN;
    const int kbase = ks * BK;

    // fragment read offsets (R7-verified swizzle: phys_db = log_db ^ ((row&15)>>1 &3))
    const int dbp = ((g ^ ((li >> 1) & 3)) << 4);
    int offA[4], offB[4];
    #pragma unroll
    for (int f = 0; f < 4; ++f) {
        offA[f] = ((wr * 64 + f * 16 + li) << 6) + dbp;
        offB[f] = ((wc * 64 + f * 16 + li) << 6) + dbp;
    }

    // staging: wave w fills tile w (zh,zl,ch,cl), lane l -> row l>>2, phys db l&3,
    // source logical db pre-swizzled so LDS write stays linear (G21).
    const int srow = l >> 2;
    const int sdb = (l & 3) ^ ((l >> 3) & 3);
    const f16* sbase = ((w < 2) ? z3 + (size_t)(nb + srow) * 512
                                : c3 + (size_t)(kbase + srow) * 512)
                       + (w & 1) * 256 + sdb * 8;
    char* const ldst0 = lds + w * 8192;

    #define STAGE(BUF, DC) do {                                                   \
        _Pragma("unroll")                                                         \
        for (int g16 = 0; g16 < 8; ++g16)                                         \
            gll16(sbase + (size_t)g16 * 8192 + (DC) * 32,                         \
                  ldst0 + (BUF) * 32768 + g16 * 1024);                            \
    } while (0)

    // numpy-exact row norms for this thread's 16 output rows
    float zn[16];
    #pragma unroll
    for (int fn = 0; fn < 4; ++fn)
        #pragma unroll
        for (int r = 0; r < 4; ++r)
            zn[fn * 4 + r] = zn2[nb + wr * 64 + fn * 16 + 4 * g + r];

    f32x4 acc1[4][4], acc2[4][4];
    #pragma unroll
    for (int a = 0; a < 4; ++a)
        #pragma unroll
        for (int b2 = 0; b2 < 4; ++b2) {
            acc1[a][b2] = f32x4{0.f, 0.f, 0.f, 0.f};
            acc2[a][b2] = f32x4{0.f, 0.f, 0.f, 0.f};
        }

    STAGE(0, 0);
    __syncthreads();

    #pragma unroll
    for (int dc = 0; dc < 8; ++dc) {
        const int buf = dc & 1;
        if (dc < 7) STAGE(buf ^ 1, dc + 1);

        const char* base = lds + buf * 32768;
        const char* zh = base, *zl = base + 8192, *ch = base + 16384, *cl = base + 24576;
        f16x8 Ah[4], Bh[4], T[4];
        #pragma unroll
        for (int f = 0; f < 4; ++f) Ah[f] = *(const f16x8*)(zh + offA[f]);
        #pragma unroll
        for (int f = 0; f < 4; ++f) Bh[f] = *(const f16x8*)(ch + offB[f]);
        #pragma unroll
        for (int fn = 0; fn < 4; ++fn)
            #pragma unroll
            for (int fk = 0; fk < 4; ++fk)
                acc1[fn][fk] = __builtin_amdgcn_mfma_f32_16x16x32_f16(
                    Ah[fn], Bh[fk], acc1[fn][fk], 0, 0, 0);
        #pragma unroll
        for (int f = 0; f < 4; ++f) T[f] = *(const f16x8*)(cl + offB[f]);
        #pragma unroll
        for (int fn = 0; fn < 4; ++fn)
            #pragma unroll
            for (int fk = 0; fk < 4; ++fk)
                acc2[fn][fk] = __builtin_amdgcn_mfma_f32_16x16x32_f16(
                    Ah[fn], T[fk], acc2[fn][fk], 0, 0, 0);
        #pragma unroll
        for (int f = 0; f < 4; ++f) T[f] = *(const f16x8*)(zl + offA[f]);
        #pragma unroll
        for (int fn = 0; fn < 4; ++fn)
            #pragma unroll
            for (int fk = 0; fk < 4; ++fk)
                acc2[fn][fk] = __builtin_amdgcn_mfma_f32_16x16x32_f16(
                    T[fn], Bh[fk], acc2[fn][fk], 0, 0, 0);
        __syncthreads();
    }
    #undef STAGE

    // fold: g_true = (acc1 + acc2/2048)/4096; v = fl(A - 2*g_true), A = fl(zn2+cn2)
    const int k0 = kbase + wc * 64;
    float cn[4];
    #pragma unroll
    for (int fk = 0; fk < 4; ++fk) cn[fk] = cn2[k0 + fk * 16 + li];

    float best[16]; int bi[16];
    #pragma unroll
    for (int fn = 0; fn < 4; ++fn)
        #pragma unroll
        for (int fk = 0; fk < 4; ++fk)
            #pragma unroll
            for (int r = 0; r < 4; ++r) {
                const float t = fmaf(acc2[fn][fk][r], 4.8828125e-4f, acc1[fn][fk][r]);
                const float A = zn[fn * 4 + r] + cn[fk];
                const float v = fmaf(t, -4.8828125e-4f, A);
                const int idx = k0 + fk * 16 + li;
                const int s = fn * 4 + r;
                if (fk == 0) { best[s] = v; bi[s] = idx; }
                else if (v < best[s] || (v == best[s] && idx < bi[s])) {
                    best[s] = v; bi[s] = idx;
                }
            }

    // butterfly min across the 16 li lanes (xor 1,2,4,8 stays within li-group)
    #pragma unroll
    for (int s = 0; s < 16; ++s) {
        float v = best[s]; int idx = bi[s];
        #pragma unroll
        for (int m = 1; m < 16; m <<= 1) {
            const float ov = __shfl_xor(v, m, 64);
            const int oi = __shfl_xor(idx, m, 64);
            if (ov < v || (ov == v && oi < idx)) { v = ov; idx = oi; }
        }
        best[s] = v; bi[s] = idx;
    }

    if (li == 0) {
        #pragma unroll
        for (int fn = 0; fn < 4; ++fn)
            #pragma unroll
            for (int r = 0; r < 4; ++r) {
                const int s = fn * 4 + r;
                const int n = nb + wr * 64 + fn * 16 + 4 * g + r;
                const unsigned long long pk =
                    ((unsigned long long)__float_as_uint(best[s]) << 32) |
                    (unsigned)bi[s];
                atomicMin(&packed[n], pk);
            }
    }
}

// --------------------------------------------------- gather + idx unpack ---
__global__ __launch_bounds__(256) void gather_reduce_kernel(
        const float* __restrict__ emb,
        const unsigned long long* __restrict__ packed,
        float* __restrict__ fidx, float* __restrict__ zq) {
    const int tid = threadIdx.x;
    const int nb = blockIdx.x * 64;
    const int nl = tid & 63;
    const int dq = tid >> 6;
    const int b = nb >> 10, hw0 = nb & (HW - 1);
    const int k = (int)(unsigned)(packed[nb + nl] & 0xffffffffULL);
    if (dq == 0) fidx[nb + nl] = (float)k;
    const float* er = emb + (size_t)k * D_DIM;
    float* ob = zq + (size_t)b * (D_DIM * HW) + hw0 + nl;
    #pragma unroll 8
    for (int dd = 0; dd < D_DIM; dd += 4) {
        const int d = dd + dq;
        ob[(size_t)d * HW] = er[d];
    }
}

// ------------------------------------------------------------- launch -----
extern "C" void kernel_launch(void* const* d_in, const int* in_sizes, int n_in,
                              void* d_out, int out_size, void* d_ws, size_t ws_size,
                              hipStream_t stream) {
    const float* z_e = (const float*)d_in[0];   // [16,256,32,32]
    const float* emb = (const float*)d_in[1];   // [8192,256]
    float* out = (float*)d_out;
    float* out_inp = out;                        // 4194304 floats
    float* out_zq  = out + 4194304;              // 4194304 floats
    float* out_idx = out + 8388608;              // 16384 floats

    // z3 fills out_zq (gather overwrites it last); c3/cn2/packed live in
    // out_inp (inp memcpy overwrites last); zn2 in out_idx (dead before
    // gather_reduce writes fidx there).
    f16*   z3  = (f16*)out_zq;                           // 16.8 MB
    f16*   c3  = (f16*)out_inp;                          // 8.4 MB
    float* cn2 = out_inp + 2097152;                      // 8192 floats
    unsigned long long* packed =
        (unsigned long long*)(out_inp + 2105344);        // 16384 u64
    float* zn2 = out_idx;                                // 16384 floats

    prep_z_kernel<<<N_TOT / 256, 256, 0, stream>>>(z_e, z3, zn2);
    prep_c_kernel<<<K_CODES / 256, 256, 0, stream>>>(emb, c3, cn2);
    init_packed_kernel<<<N_TOT / 256, 256, 0, stream>>>(packed);
    vq_mfma_kernel<<<dim3(KSPLIT, N_TOT / BN), 256, 0, stream>>>(
        z3, c3, zn2, cn2, packed);
    gather_reduce_kernel<<<N_TOT / 64, 256, 0, stream>>>(emb, packed, out_idx, out_zq);
    hipMemcpyAsync(out_inp, z_e, (size_t)N_TOT * D_DIM * sizeof(float),
                   hipMemcpyDeviceToDevice, stream);
}

// Round 9
// 304.810 us; speedup vs baseline: 1.8908x; 1.8908x over previous
//
#include <hip/hip_runtime.h>
#include <cstdint>

#define K_CODES 8192
#define D_DIM   256
#define N_TOT   16384
#define HW      1024
#define KSPLIT  8
#define BN      128
#define BK      128
#define KT_PER  8

typedef _Float16 f16;
typedef _Float16 f16x8 __attribute__((ext_vector_type(8)));
typedef float    f32x4 __attribute__((ext_vector_type(4)));

// ---------------------------------------------------------------------------
// Tiled operand layout ("LDS image"): per plane (hi/lo) and dc-chunk (32 d),
// rows in 16-row groups: [grp][g(4)][row16][16B]  (1 KB per group).
//   z: plane stride 8*1048576 B, dc stride 1048576 B (16384 rows)
//   c: plane stride 8*524288  B, dc stride 524288  B (8192 rows)
// Staging reads are then fully contiguous 1 KB per global_load_lds, and
// fragment reads are wave-contiguous 1 KB (2-way bank aliasing = free).
// Split values identical to R7 (verified): z = h + lo*2^-11; c*4096 = h + lo*2^-11.
// ---------------------------------------------------------------------------

__global__ __launch_bounds__(64) void prep_z_kernel(const float* __restrict__ zr,
                                                    char* __restrict__ zT,
                                                    float* __restrict__ zn2) {
    #pragma clang fp contract(off)
    const int n = blockIdx.x * 64 + threadIdx.x;
    const int b = n >> 10, hw = n & (HW - 1);
    const float* p = zr + (size_t)b * (D_DIM * HW) + hw;
    const size_t grp = (size_t)(n >> 4), l16 = (size_t)(n & 15);
    float blk0 = 0.f, r[8];
    #pragma unroll
    for (int dc = 0; dc < 8; ++dc) {
        f16 hib[32], lob[32];
        #pragma unroll
        for (int j = 0; j < 32; ++j) {
            const int d = dc * 32 + j;
            const float v = p[(size_t)d * HW];
            const f16 h = (f16)v;
            hib[j] = h;
            lob[j] = (f16)((v - (float)h) * 2048.0f);
            const float sq = v * v;                 // numpy pairwise (verified R6)
            const int dm = d & 127;
            if (dm < 8) r[dm] = sq; else r[dm & 7] += sq;
            if (dm == 127) {
                const float s = ((r[0] + r[1]) + (r[2] + r[3])) +
                                ((r[4] + r[5]) + (r[6] + r[7]));
                if (d < 128) blk0 = s; else zn2[n] = blk0 + s;
            }
        }
        char* zb = zT + (size_t)dc * 1048576 + grp * 1024 + l16 * 16;
        #pragma unroll
        for (int g = 0; g < 4; ++g) {
            *reinterpret_cast<f16x8*>(zb + g * 256) =
                *reinterpret_cast<const f16x8*>(&hib[g * 8]);
            *reinterpret_cast<f16x8*>(zb + 8388608 + g * 256) =
                *reinterpret_cast<const f16x8*>(&lob[g * 8]);
        }
    }
}

__global__ __launch_bounds__(64) void prep_c_kernel(const float* __restrict__ emb,
                                                    char* __restrict__ cT,
                                                    float* __restrict__ cn2) {
    #pragma clang fp contract(off)
    const int k = blockIdx.x * 64 + threadIdx.x;
    const float* p = emb + (size_t)k * D_DIM;
    const size_t grp = (size_t)(k >> 4), l16 = (size_t)(k & 15);
    float blk0 = 0.f, r[8];
    #pragma unroll
    for (int dc = 0; dc < 8; ++dc) {
        f16 hib[32], lob[32];
        #pragma unroll
        for (int jj = 0; jj < 32; jj += 4) {
            const float4 v4 = *reinterpret_cast<const float4*>(p + dc * 32 + jj);
            const float vv[4] = {v4.x, v4.y, v4.z, v4.w};
            #pragma unroll
            for (int e = 0; e < 4; ++e) {
                const int j = jj + e, d = dc * 32 + j;
                const float v = vv[e];
                const float vs = v * 4096.0f;
                const f16 h = (f16)vs;
                hib[j] = h;
                lob[j] = (f16)((vs - (float)h) * 2048.0f);
                const float sq = v * v;
                const int dm = d & 127;
                if (dm < 8) r[dm] = sq; else r[dm & 7] += sq;
                if (dm == 127) {
                    const float s = ((r[0] + r[1]) + (r[2] + r[3])) +
                                    ((r[4] + r[5]) + (r[6] + r[7]));
                    if (d < 128) blk0 = s; else cn2[k] = blk0 + s;
                }
            }
        }
        char* cb = cT + (size_t)dc * 524288 + grp * 1024 + l16 * 16;
        #pragma unroll
        for (int g = 0; g < 4; ++g) {
            *reinterpret_cast<f16x8*>(cb + g * 256) =
                *reinterpret_cast<const f16x8*>(&hib[g * 8]);
            *reinterpret_cast<f16x8*>(cb + 4194304 + g * 256) =
                *reinterpret_cast<const f16x8*>(&lob[g * 8]);
        }
    }
}

__device__ __forceinline__ void gll16(const void* g, void* l) {
    __builtin_amdgcn_global_load_lds(
        (const __attribute__((address_space(1))) unsigned int*)g,
        (__attribute__((address_space(3))) unsigned int*)l, 16, 0, 0);
}

// ---------------------------------------------------------------------------
// Main MFMA kernel: R7 structure (grid (8,128), KT_PER=8, dbuf, partials),
// new contiguous staging + image-layout fragment reads. Numerics bit-identical
// to the R7 kernel that passed with exact indices.
// ---------------------------------------------------------------------------
__global__ __launch_bounds__(256, 2) void vq_mfma_kernel(
        const char* __restrict__ zT, const char* __restrict__ cT,
        const float* __restrict__ zn2, const float* __restrict__ cn2,
        float* __restrict__ pvals, int* __restrict__ pidx) {
    __shared__ __align__(16) char lds[2 * 32768];

    const int tid = threadIdx.x;
    const int w = tid >> 6, l = tid & 63;
    const int wr = w >> 1, wc = w & 1;
    const int g = l >> 4, li = l & 15;
    const int ks = blockIdx.x;
    const int nb = blockIdx.y * BN;
    const int kbase = ks * (K_CODES / KSPLIT);

    // staging roles: wave 0 -> z-hi, 1 -> z-lo, 2 -> c-hi, 3 -> c-lo
    const int plane = w & 1;
    const char* sZ = zT + (size_t)plane * 8388608 + (size_t)(nb >> 4) * 1024 + l * 16;
    const char* sC = cT + (size_t)plane * 4194304 + l * 16;
    char* const ldst = lds + w * 8192;

    #define STAGE(BUF, KT, DC) do {                                              \
        const char* s_ = (w < 2)                                                 \
            ? (sZ + (size_t)(DC) * 1048576)                                      \
            : (sC + (size_t)(DC) * 524288 +                                      \
               (size_t)((kbase + (KT) * BK) >> 4) * 1024);                       \
        char* d_ = ldst + (BUF) * 32768;                                         \
        _Pragma("unroll")                                                        \
        for (int i = 0; i < 8; ++i) gll16(s_ + i * 1024, d_ + i * 1024);         \
    } while (0)

    // numpy-exact row norms for this thread's 16 output rows (C/D row = 4*g + r)
    float zn[16];
    #pragma unroll
    for (int fn = 0; fn < 4; ++fn)
        #pragma unroll
        for (int r = 0; r < 4; ++r)
            zn[fn * 4 + r] = zn2[nb + wr * 64 + fn * 16 + 4 * g + r];

    float best[16]; int bi[16];
    #pragma unroll
    for (int i = 0; i < 16; ++i) { best[i] = 3.4e38f; bi[i] = 0; }

    f32x4 acc1[4][4], acc2[4][4];
    #pragma unroll
    for (int a = 0; a < 4; ++a)
        #pragma unroll
        for (int b2 = 0; b2 < 4; ++b2) {
            acc1[a][b2] = f32x4{0.f, 0.f, 0.f, 0.f};
            acc2[a][b2] = f32x4{0.f, 0.f, 0.f, 0.f};
        }

    STAGE(0, 0, 0);
    __syncthreads();

    int buf = 0;
    for (int it = 0; it < KT_PER * 8; ++it) {
        const int kt = it >> 3, dc = it & 7;
        if (it + 1 < KT_PER * 8) STAGE(buf ^ 1, (it + 1) >> 3, (it + 1) & 7);

        const char* base = lds + buf * 32768;
        // fragment reads: wave-contiguous 1 KB per frag (group = wr*4+f / wc*4+f)
        f16x8 Ah[4], Bh[4], T[4];
        #pragma unroll
        for (int f = 0; f < 4; ++f)
            Ah[f] = *reinterpret_cast<const f16x8*>(base + (wr * 4 + f) * 1024 + l * 16);
        #pragma unroll
        for (int f = 0; f < 4; ++f)
            Bh[f] = *reinterpret_cast<const f16x8*>(base + 16384 + (wc * 4 + f) * 1024 + l * 16);
        #pragma unroll
        for (int fn = 0; fn < 4; ++fn)
            #pragma unroll
            for (int fk = 0; fk < 4; ++fk)
                acc1[fn][fk] = __builtin_amdgcn_mfma_f32_16x16x32_f16(
                    Ah[fn], Bh[fk], acc1[fn][fk], 0, 0, 0);
        #pragma unroll
        for (int f = 0; f < 4; ++f)
            T[f] = *reinterpret_cast<const f16x8*>(base + 24576 + (wc * 4 + f) * 1024 + l * 16);
        #pragma unroll
        for (int fn = 0; fn < 4; ++fn)
            #pragma unroll
            for (int fk = 0; fk < 4; ++fk)
                acc2[fn][fk] = __builtin_amdgcn_mfma_f32_16x16x32_f16(
                    Ah[fn], T[fk], acc2[fn][fk], 0, 0, 0);
        #pragma unroll
        for (int f = 0; f < 4; ++f)
            T[f] = *reinterpret_cast<const f16x8*>(base + 8192 + (wr * 4 + f) * 1024 + l * 16);
        #pragma unroll
        for (int fn = 0; fn < 4; ++fn)
            #pragma unroll
            for (int fk = 0; fk < 4; ++fk)
                acc2[fn][fk] = __builtin_amdgcn_mfma_f32_16x16x32_f16(
                    T[fn], Bh[fk], acc2[fn][fk], 0, 0, 0);

        if (dc == 7) {
            // g_true = (acc1 + acc2*2^-11)/4096; v = fl(A - 2*g_true) (R7-exact)
            const int k0 = kbase + kt * BK + wc * 64;
            float cn[4];
            #pragma unroll
            for (int fk = 0; fk < 4; ++fk) cn[fk] = cn2[k0 + fk * 16 + li];
            #pragma unroll
            for (int fn = 0; fn < 4; ++fn)
                #pragma unroll
                for (int fk = 0; fk < 4; ++fk) {
                    #pragma unroll
                    for (int r = 0; r < 4; ++r) {
                        const float t = fmaf(acc2[fn][fk][r], 4.8828125e-4f,
                                             acc1[fn][fk][r]);
                        const float A = zn[fn * 4 + r] + cn[fk];
                        const float v = fmaf(t, -4.8828125e-4f, A);
                        if (v < best[fn * 4 + r]) {
                            best[fn * 4 + r] = v;
                            bi[fn * 4 + r] = k0 + fk * 16 + li;
                        }
                    }
                    acc1[fn][fk] = f32x4{0.f, 0.f, 0.f, 0.f};
                    acc2[fn][fk] = f32x4{0.f, 0.f, 0.f, 0.f};
                }
        }
        __syncthreads();
        buf ^= 1;
    }
    #undef STAGE

    // butterfly min across the 16 li lanes (R7-verified)
    #pragma unroll
    for (int s = 0; s < 16; ++s) {
        float v = best[s]; int idx = bi[s];
        #pragma unroll
        for (int m = 1; m < 16; m <<= 1) {
            const float ov = __shfl_xor(v, m, 64);
            const int oi = __shfl_xor(idx, m, 64);
            if (ov < v || (ov == v && oi < idx)) { v = ov; idx = oi; }
        }
        best[s] = v; bi[s] = idx;
    }

    // cross-wave (wc) merge via LDS, store per-ks partials (R7-verified)
    float* mv = (float*)lds;
    int* mi = (int*)(lds + 512);
    if (wc == 1 && li == 0) {
        #pragma unroll
        for (int fn = 0; fn < 4; ++fn)
            #pragma unroll
            for (int r = 0; r < 4; ++r) {
                const int nl = wr * 64 + fn * 16 + 4 * g + r;
                mv[nl] = best[fn * 4 + r]; mi[nl] = bi[fn * 4 + r];
            }
    }
    __syncthreads();
    if (wc == 0 && li == 0) {
        #pragma unroll
        for (int fn = 0; fn < 4; ++fn)
            #pragma unroll
            for (int r = 0; r < 4; ++r) {
                const int nl = wr * 64 + fn * 16 + 4 * g + r;
                float v = best[fn * 4 + r]; int idx = bi[fn * 4 + r];
                const float ov = mv[nl]; const int oi = mi[nl];
                if (ov < v || (ov == v && oi < idx)) { v = ov; idx = oi; }
                const int n = nb + nl;
                pvals[(size_t)n * KSPLIT + ks] = v;
                pidx[(size_t)n * KSPLIT + ks] = idx;
            }
    }
}

// ------------------------------------------------------- ksplit reduce ----
__global__ __launch_bounds__(256) void reduce_kernel(const float* __restrict__ pvals,
                                                     const int* __restrict__ pidx,
                                                     float* __restrict__ fidx) {
    const int n = blockIdx.x * 256 + threadIdx.x;
    float bv = 3.4e38f; int bidx = 0;
    #pragma unroll
    for (int s = 0; s < KSPLIT; ++s) {
        const float v = pvals[(size_t)n * KSPLIT + s];
        const int i = pidx[(size_t)n * KSPLIT + s];
        if (v < bv || (v == bv && i < bidx)) { bv = v; bidx = i; }
    }
    fidx[n] = (float)bidx;
}

// ------------------------------------------------------------- gather -----
__global__ __launch_bounds__(256) void gather_kernel(const float* __restrict__ emb,
                                                     const float* __restrict__ fidx,
                                                     float* __restrict__ zq) {
    const int tid = threadIdx.x;
    const int nb = blockIdx.x * 64;
    const int nl = tid & 63;
    const int dq = tid >> 6;
    const int b = nb >> 10, hw0 = nb & (HW - 1);
    const int k = (int)fidx[nb + nl];
    const float* er = emb + (size_t)k * D_DIM;
    float* ob = zq + (size_t)b * (D_DIM * HW) + hw0 + nl;
    #pragma unroll 8
    for (int dd = 0; dd < D_DIM; dd += 4) {
        const int d = dd + dq;
        ob[(size_t)d * HW] = er[d];
    }
}

// ------------------------------------------------------------- launch -----
extern "C" void kernel_launch(void* const* d_in, const int* in_sizes, int n_in,
                              void* d_out, int out_size, void* d_ws, size_t ws_size,
                              hipStream_t stream) {
    const float* z_e = (const float*)d_in[0];   // [16,256,32,32]
    const float* emb = (const float*)d_in[1];   // [8192,256]
    float* out = (float*)d_out;
    float* out_inp = out;                        // 4194304 floats (16 MB)
    float* out_zq  = out + 4194304;              // 4194304 floats (16 MB)
    float* out_idx = out + 8388608;              // 16384 floats

    // zT fills out_zq exactly (2*8*16384*64 B = 16777216 B); gather overwrites
    // it last. cT (8388608 B) + norms + partials live in out_inp; the inp
    // memcpy overwrites them last.
    char*  zT    = (char*)out_zq;
    char*  cT    = (char*)out_inp;
    float* cn2   = out_inp + 2097152;            // 8192 floats
    float* zn2   = out_inp + 2105344;            // 16384 floats
    float* pvals = out_inp + 2121728;            // 131072 floats
    int*   pidx  = (int*)(out_inp + 2252800);    // 131072 ints

    prep_z_kernel<<<N_TOT / 64, 64, 0, stream>>>(z_e, zT, zn2);
    prep_c_kernel<<<K_CODES / 64, 64, 0, stream>>>(emb, cT, cn2);
    vq_mfma_kernel<<<dim3(KSPLIT, N_TOT / BN), 256, 0, stream>>>(
        zT, cT, zn2, cn2, pvals, pidx);
    reduce_kernel<<<N_TOT / 256, 256, 0, stream>>>(pvals, pidx, out_idx);
    gather_kernel<<<N_TOT / 64, 256, 0, stream>>>(emb, out_idx, out_zq);
    hipMemcpyAsync(out_inp, z_e, (size_t)N_TOT * D_DIM * sizeof(float),
                   hipMemcpyDeviceToDevice, stream);
}